// Round 8
// baseline (3528.661 us; speedup 1.0000x reference)
//
#include <hip/hip_runtime.h>
#include <math.h>

#define M_TOTAL 2048
#define N_TOTAL 1024
#define TSEQ    80
#define EMB_D   512
#define VOCAB   50000
#define EW_ROWS 50048            // VOCAB padded to 128
#define BK      64

typedef __attribute__((ext_vector_type(8))) short bf16x8;
typedef __attribute__((ext_vector_type(4))) float f32x4;

__device__ __forceinline__ ushort f2bf(float f) {
    union { float f; unsigned u; } v; v.f = f;
    unsigned r = v.u + 0x7FFFu + ((v.u >> 16) & 1u);
    return (ushort)(r >> 16);
}
__device__ __forceinline__ float bf2f(ushort h) {
    union { unsigned u; float f; } v; v.u = ((unsigned)h) << 16;
    return v.f;
}
__device__ __forceinline__ void gload_lds16(const ushort* g, ushort* l) {
    __builtin_amdgcn_global_load_lds(
        (const __attribute__((address_space(1))) void*)g,
        (__attribute__((address_space(3))) void*)l, 16, 0, 0);
}
#define VMC4()  asm volatile("s_waitcnt vmcnt(4)" ::: "memory")
#define VMC0()  asm volatile("s_waitcnt vmcnt(0)" ::: "memory")
#define SBAR()  __builtin_amdgcn_s_barrier()
#define SCHED0() __builtin_amdgcn_sched_barrier(0)

// ---------------------------------------------------------------------------
// Shared GEMM core: 128x128 tile, 256 thr (4 waves 2x2, wave-tile 64x64).
// A: triple-buffered (depth-2 cover, h-state panels), B: double-buffered
// (depth-1 cover, XCD-pinned L2-resident weight strips). Derived waits:
//   per chunk: vmcnt(4) [A(c),B(c) landed; A(c+1) stays in flight] ;
//   s_barrier ; stage_B(c+1) ; stage_A(c+2) ; compute(c).
// LDS = 3*16 + 2*16 = 80 KB -> exactly 2 blocks/CU.
// ga/gb: per-thread row-base offsets (XOR-pre-swizzled source granule).
// ---------------------------------------------------------------------------
template<int NC>
__device__ __forceinline__ void gemm_core(
    f32x4 (&acc)[4][4],
    const ushort* __restrict__ A, const size_t* __restrict__ ga,
    const ushort* __restrict__ B, const size_t* __restrict__ gb,
    int w, int l,
    ushort (*As)[128 * BK], ushort (*Bs)[128 * BK])
{
    const int wr = w >> 1, wc = w & 1;
    auto stA = [&](int c, int buf) {
        const int k0 = c << 6;
        #pragma unroll
        for (int j = 0; j < 4; ++j)
            gload_lds16(A + ga[j] + k0, &As[buf][(w * 32 + j * 8) * BK + l * 8]);
    };
    auto stB = [&](int c, int buf) {
        const int k0 = c << 6;
        #pragma unroll
        for (int j = 0; j < 4; ++j)
            gload_lds16(B + gb[j] + k0, &Bs[buf][(w * 32 + j * 8) * BK + l * 8]);
    };
    stA(0, 0); stB(0, 0); stA(1, 1);
    #pragma unroll
    for (int c = 0; c < NC; ++c) {
        if (c + 1 < NC) { VMC4(); } else { VMC0(); }
        SBAR(); SCHED0();
        if (c + 1 < NC) stB(c + 1, (c + 1) & 1);
        if (c + 2 < NC) stA(c + 2, (c + 2) % 3);
        #pragma unroll
        for (int kf = 0; kf < 2; ++kf) {
            const int ke = kf * 32 + (l >> 4) * 8;
            bf16x8 a[4], b[4];
            #pragma unroll
            for (int mf = 0; mf < 4; ++mf) {
                const int row = wr * 64 + mf * 16 + (l & 15);
                a[mf] = *(const bf16x8*)&As[c % 3][row * BK + (ke ^ ((row & 7) << 3))];
            }
            #pragma unroll
            for (int nf = 0; nf < 4; ++nf) {
                const int row = wc * 64 + nf * 16 + (l & 15);
                b[nf] = *(const bf16x8*)&Bs[c & 1][row * BK + (ke ^ ((row & 7) << 3))];
            }
            #pragma unroll
            for (int mf = 0; mf < 4; ++mf)
                #pragma unroll
                for (int nf = 0; nf < 4; ++nf)
                    acc[mf][nf] = __builtin_amdgcn_mfma_f32_16x16x32_bf16(
                        a[mf], b[nf], acc[mf][nf], 0, 0, 0);
        }
    }
}

// ---------------------------------------------------------------------------
// Fused per-step kernel, grid 448:
//   bid 0..383 : GEMM jobs. n = bid&7 (XCD-pinned 128-col weight strip),
//                rest = bid>>3, job = rest%3, m = rest/3.
//     job0 (J1): h1[i]   = tanh(xw1[i] + h1[i-1]@U1 + b1)   [in-place slab]
//     job1 (J2): xw2[i-1]= h1[i-1]@W2                       [fp32 raw store]
//     job2 (J3): h2[i-2] = tanh(xw2[i-2] + h2[i-3]@U2 + b2)
//   bid 384..447 : J0 gather xw1[i+1] rows from EW1 into sl_next.
// ---------------------------------------------------------------------------
__global__ __launch_bounds__(256) void fused_step(
    const ushort* __restrict__ EW1,
    const int* __restrict__ tok,
    const ushort* __restrict__ sl_prev,   // h1[i-1] (h1zero at i==0)
    ushort* __restrict__ sl_cur,          // xw1[i] -> h1[i]
    ushort* __restrict__ sl_next,         // J0 dst: xw1[i+1]
    const ushort* __restrict__ U1T, const float* __restrict__ b1,
    const ushort* __restrict__ W2T,
    float* __restrict__ xw2_dst,
    const float* __restrict__ xw2_src,
    const ushort* __restrict__ U2T, const float* __restrict__ b2,
    const ushort* __restrict__ h2prev,
    ushort* __restrict__ h2dst,
    int i)
{
    __shared__ ushort As[3][128 * BK];   // 48 KB
    __shared__ ushort Bs[2][128 * BK];   // 32 KB
    const int tid = threadIdx.x;
    const int bid = blockIdx.x;

    if (bid >= 384) {                    // ---- J0: gather xw1[i+1]
        if (i > TSEQ - 2) return;
        const int b = (bid - 384) * 32 + (tid >> 3);
        const int token = tok[b * TSEQ + i + 1];
        const uint4* src = (const uint4*)(EW1 + (size_t)token * N_TOTAL);
        uint4* dst = (uint4*)(sl_next + (size_t)b * N_TOTAL);
        #pragma unroll
        for (int g = 0; g < 16; ++g)
            dst[(tid & 7) + g * 8] = src[(tid & 7) + g * 8];
        return;
    }

    const int w = tid >> 6, l = tid & 63;
    const int n = bid & 7, rest = bid >> 3;
    const int job = rest % 3;
    const int m = rest / 3;
    const int bm0 = m << 7, bn0 = n << 7;

    if (job == 0 && i > TSEQ - 1) return;
    if (job == 1 && (i < 1 || i > TSEQ)) return;
    if (job == 2 && i < 2) return;

    const ushort* A; const ushort* B;
    if (job == 0)      { A = sl_prev; B = U1T; }
    else if (job == 1) { A = sl_prev; B = W2T; }
    else               { A = h2prev;  B = U2T; }

    const int lr = l >> 3;
    const int se = ((l & 7) ^ lr) << 3;
    size_t ga[4], gb[4];
    #pragma unroll
    for (int j = 0; j < 4; ++j) {
        ga[j] = (size_t)(bm0 + w * 32 + j * 8 + lr) * N_TOTAL + se;
        gb[j] = (size_t)(bn0 + w * 32 + j * 8 + lr) * N_TOTAL + se;
    }

    f32x4 acc[4][4] = {};
    gemm_core<16>(acc, A, ga, B, gb, w, l, As, Bs);

    const int wr = w >> 1, wc = w & 1;
    #pragma unroll
    for (int nf = 0; nf < 4; ++nf) {
        const int col = bn0 + wc * 64 + nf * 16 + (l & 15);
        #pragma unroll
        for (int mf = 0; mf < 4; ++mf) {
            const int rb = bm0 + wr * 64 + mf * 16 + (l >> 4) * 4;
            #pragma unroll
            for (int r = 0; r < 4; ++r) {
                const size_t idx = (size_t)(rb + r) * N_TOTAL + col;
                if (job == 0)
                    sl_cur[idx] = f2bf(tanhf(acc[mf][nf][r] + bf2f(sl_cur[idx]) + b1[col]));
                else if (job == 1)
                    xw2_dst[idx] = acc[mf][nf][r];
                else
                    h2dst[idx] = f2bf(tanhf(acc[mf][nf][r] + xw2_src[idx] + b2[col]));
            }
        }
    }
}

// ---------------------------------------------------------------------------
// EW1[v][n] = embb[v] @ W1^T  (one-time, M=50048 padded, K=512, NC=8)
// ---------------------------------------------------------------------------
__global__ __launch_bounds__(256) void ew1_gemm(
    ushort* __restrict__ EW1,
    const ushort* __restrict__ embb,     // [50000][512]
    const ushort* __restrict__ W1T)      // [1024][512]
{
    __shared__ ushort As[3][128 * BK];
    __shared__ ushort Bs[2][128 * BK];
    const int tid = threadIdx.x;
    const int w = tid >> 6, l = tid & 63;
    const int bid = blockIdx.x;
    const int n = bid & 7, m = bid >> 3;        // m 0..390
    const int bm0 = m << 7, bn0 = n << 7;

    const int lr = l >> 3;
    const int se = ((l & 7) ^ lr) << 3;
    size_t ga[4], gb[4];
    #pragma unroll
    for (int j = 0; j < 4; ++j) {
        int row = bm0 + w * 32 + j * 8 + lr;
        if (row >= VOCAB) row = VOCAB - 1;      // clamp (results discarded)
        ga[j] = (size_t)row * EMB_D + se;
        gb[j] = (size_t)(bn0 + w * 32 + j * 8 + lr) * EMB_D + se;
    }

    f32x4 acc[4][4] = {};
    gemm_core<8>(acc, embb, ga, W1T, gb, w, l, As, Bs);

    const int wr = w >> 1, wc = w & 1;
    #pragma unroll
    for (int nf = 0; nf < 4; ++nf) {
        const int col = bn0 + wc * 64 + nf * 16 + (l & 15);
        #pragma unroll
        for (int mf = 0; mf < 4; ++mf) {
            const int rb = bm0 + wr * 64 + mf * 16 + (l >> 4) * 4;
            #pragma unroll
            for (int r = 0; r < 4; ++r)
                if (rb + r < VOCAB)
                    EW1[(size_t)(rb + r) * N_TOTAL + col] = f2bf(acc[mf][nf][r]);
        }
    }
}

// gather xw1[t] into slab (prologue, t=0)
__global__ __launch_bounds__(256) void gather_xw1(
    ushort* __restrict__ dst, const ushort* __restrict__ EW1,
    const int* __restrict__ tok, int t)
{
    const int b = blockIdx.x * 32 + (threadIdx.x >> 3);
    const int token = tok[b * TSEQ + t];
    const uint4* src = (const uint4*)(EW1 + (size_t)token * N_TOTAL);
    uint4* d = (uint4*)(dst + (size_t)b * N_TOTAL);
    #pragma unroll
    for (int g = 0; g < 16; ++g)
        d[(threadIdx.x & 7) + g * 8] = src[(threadIdx.x & 7) + g * 8];
}

// emb fp32 -> bf16 (50000*512/8/256 = 12500 blocks)
__global__ __launch_bounds__(256) void emb_convert(
    ushort* __restrict__ dst, const float* __restrict__ src)
{
    const size_t i = ((size_t)blockIdx.x * 256 + threadIdx.x) * 8;
    const float4 v0 = *(const float4*)(src + i);
    const float4 v1 = *(const float4*)(src + i + 4);
    const unsigned w0 = f2bf(v0.x) | (f2bf(v0.y) << 16);
    const unsigned w1 = f2bf(v0.z) | (f2bf(v0.w) << 16);
    const unsigned w2 = f2bf(v1.x) | (f2bf(v1.y) << 16);
    const unsigned w3 = f2bf(v1.z) | (f2bf(v1.w) << 16);
    *(uint4*)(dst + i) = make_uint4(w0, w1, w2, w3);
}

// W [K][N] fp32 -> WT [N][K] bf16
__global__ __launch_bounds__(256) void transpose_convert(
    ushort* __restrict__ outT, const float* __restrict__ in, int K, int N)
{
    __shared__ float tile[64][65];
    const int tiles_n = N >> 6;
    const int k0 = (blockIdx.x / tiles_n) << 6;
    const int n0 = (blockIdx.x % tiles_n) << 6;
    const int tid = threadIdx.x;
    const int r = tid >> 4, c = (tid & 15) << 2;
    #pragma unroll
    for (int i = 0; i < 4; ++i) {
        const float4 v = *(const float4*)(in + (size_t)(k0 + r + i * 16) * N + n0 + c);
        tile[r + i * 16][c + 0] = v.x;
        tile[r + i * 16][c + 1] = v.y;
        tile[r + i * 16][c + 2] = v.z;
        tile[r + i * 16][c + 3] = v.w;
    }
    __syncthreads();
    const int n = tid >> 2, ks = (tid & 3) << 4;
    unsigned pk[8];
    #pragma unroll
    for (int j = 0; j < 8; ++j) {
        const unsigned lo = f2bf(tile[ks + 2 * j][n]);
        const unsigned hi = f2bf(tile[ks + 2 * j + 1][n]);
        pk[j] = lo | (hi << 16);
    }
    ushort* dst = outT + (size_t)(n0 + n) * K + k0 + ks;
    *(uint4*)(dst + 0) = make_uint4(pk[0], pk[1], pk[2], pk[3]);
    *(uint4*)(dst + 8) = make_uint4(pk[4], pk[5], pk[6], pk[7]);
}

__global__ __launch_bounds__(256) void out_kernel(
    float* __restrict__ out, const ushort* __restrict__ h2,
    const float* __restrict__ Wo, const float* __restrict__ bo)
{
    const int row  = blockIdx.x * 4 + (threadIdx.x >> 6);
    const int lane = threadIdx.x & 63;
    const ushort* hr = h2 + (size_t)row * N_TOTAL;
    float s = 0.f;
    for (int k = lane; k < N_TOTAL; k += 64)
        s += bf2f(hr[k]) * Wo[k];
    #pragma unroll
    for (int off = 32; off; off >>= 1)
        s += __shfl_down(s, off);
    if (lane == 0)
        out[row] = 1.f / (1.f + expf(-(s + bo[0])));
}

extern "C" void kernel_launch(void* const* d_in, const int* in_sizes, int n_in,
                              void* d_out, int out_size, void* d_ws, size_t ws_size,
                              hipStream_t stream) {
    const int*   tokens = (const int*)  d_in[0];
    const float* emb    = (const float*)d_in[1];
    const float* W1     = (const float*)d_in[2];
    const float* U1     = (const float*)d_in[3];
    const float* b1     = (const float*)d_in[4];
    const float* W2     = (const float*)d_in[5];
    const float* U2     = (const float*)d_in[6];
    const float* b2     = (const float*)d_in[7];
    const float* Wo     = (const float*)d_in[8];
    const float* bo     = (const float*)d_in[9];
    float* out = (float*)d_out;

    char* ws = (char*)d_ws;
    const size_t HB = (size_t)M_TOTAL * N_TOTAL * sizeof(ushort);      // 4 MB
    size_t off = 0;
    ushort* h1zero = (ushort*)(ws + off); off += HB;
    ushort* h2x0   = (ushort*)(ws + off); off += HB;
    ushort* h2x1   = (ushort*)(ws + off); off += HB;
    ushort* ring0  = (ushort*)(ws + off); off += HB;
    ushort* ring1  = (ushort*)(ws + off); off += HB;
    ushort* ring2  = (ushort*)(ws + off); off += HB;
    float*  xw2f0  = (float*)(ws + off);  off += (size_t)M_TOTAL * N_TOTAL * 4;
    float*  xw2f1  = (float*)(ws + off);  off += (size_t)M_TOTAL * N_TOTAL * 4;
    ushort* W1T = (ushort*)(ws + off); off += (size_t)N_TOTAL * EMB_D   * 2;
    ushort* U1T = (ushort*)(ws + off); off += (size_t)N_TOTAL * N_TOTAL * 2;
    ushort* W2T = (ushort*)(ws + off); off += (size_t)N_TOTAL * N_TOTAL * 2;
    ushort* U2T = (ushort*)(ws + off); off += (size_t)N_TOTAL * N_TOTAL * 2;
    ushort* embb = (ushort*)(ws + off); off += (size_t)VOCAB * EMB_D * 2;
    ushort* EW1  = (ushort*)(ws + off); off += (size_t)EW_ROWS * N_TOTAL * 2;

    ushort* ring[3] = { ring0, ring1, ring2 };
    float*  xw2f[2] = { xw2f0, xw2f1 };
    ushort* h2x[2]  = { h2x0, h2x1 };

    hipMemsetAsync(h1zero, 0, HB, stream);
    hipMemsetAsync(h2x1,   0, HB, stream);   // h2[-1] zeros (read at i==2)

    emb_convert<<<dim3(12500), 256, 0, stream>>>(embb, emb);
    transpose_convert<<<dim3((EMB_D  / 64) * (N_TOTAL / 64)), 256, 0, stream>>>(W1T, W1, EMB_D,   N_TOTAL);
    transpose_convert<<<dim3((N_TOTAL / 64) * (N_TOTAL / 64)), 256, 0, stream>>>(U1T, U1, N_TOTAL, N_TOTAL);
    transpose_convert<<<dim3((N_TOTAL / 64) * (N_TOTAL / 64)), 256, 0, stream>>>(W2T, W2, N_TOTAL, N_TOTAL);
    transpose_convert<<<dim3((N_TOTAL / 64) * (N_TOTAL / 64)), 256, 0, stream>>>(U2T, U2, N_TOTAL, N_TOTAL);

    ew1_gemm<<<dim3((EW_ROWS / 128) * 8), 256, 0, stream>>>(EW1, embb, W1T);
    gather_xw1<<<dim3(64), 256, 0, stream>>>(ring[0], EW1, tokens, 0);

    for (int i = 0; i <= TSEQ + 1; ++i) {
        const ushort* sl_prev = (i == 0) ? h1zero : ring[(i - 1) % 3];
        ushort* sl_cur  = ring[i % 3];
        ushort* sl_next = ring[(i + 1) % 3];
        float* xw2_dst  = xw2f[(i - 1) & 1];
        const float* xw2_src = xw2f[(i - 2) & 1];
        const ushort* h2prev = h2x[(i - 3) & 1];
        ushort* h2dst = h2x[(i - 2) & 1];
        fused_step<<<dim3(448), 256, 0, stream>>>(
            EW1, tokens, sl_prev, sl_cur, sl_next,
            U1T, b1, W2T, xw2_dst, xw2_src, U2T, b2, h2prev, h2dst, i);
    }

    out_kernel<<<dim3(M_TOTAL / 4), dim3(256), 0, stream>>>(out, h2x[1], Wo, bo);
}